// Round 8
// baseline (530.638 us; speedup 1.0000x reference)
//
#include <hip/hip_runtime.h>

#define HH 192
#define WW 192
#define CC 64
#define NB 1024

typedef __bf16 bf16x8 __attribute__((ext_vector_type(8)));
typedef float  f32x4  __attribute__((ext_vector_type(4)));

__device__ __forceinline__ unsigned short f2bf(float f) {
    unsigned int u = __builtin_bit_cast(unsigned int, f);
    u += 0x7FFFu + ((u >> 16) & 1u);   // round-to-nearest-even
    return (unsigned short)(u >> 16);
}

// LDS bank swizzle: channel-group XOR by (px & 7). Keeps 16B alignment,
// verified conflict-free in R5/R6/R7 (SQ_LDS_BANK_CONFLICT = 0).
#define SWZ(px, c) ((c) ^ (((px) & 7) << 3))

// ---------------------------------------------------------------------------
// Weight pre-transpose: w f32 [tap][c][o] (tap=dy*3+dx, 64x64) -> bf16
// WT[tap][kc][nt][lane][j]  with c = kc*32 + (lane>>4)*8 + j, o = nt*16 + (lane&15)
// ---------------------------------------------------------------------------
__global__ __launch_bounds__(256) void wt_kernel(const float* __restrict__ w,
                                                 unsigned short* __restrict__ wt) {
    int idx = blockIdx.x * 256 + threadIdx.x;      // 0 .. 36863
    int j    = idx & 7;
    int lane = (idx >> 3) & 63;
    int nt   = (idx >> 9) & 3;
    int kc   = (idx >> 11) & 1;
    int tap  = idx >> 12;
    int c = kc * 32 + ((lane >> 4) << 3) + j;
    int o = (nt << 4) + (lane & 15);
    wt[idx] = f2bf(w[(tap * 64 + c) * 64 + o]);
}

// ---------------------------------------------------------------------------
// Out-weight transpose: ow f32 [tap][c][3] -> bf16 B-frag layout, cols padded
// to 16: WTo[tap][kc][lane][j]
// ---------------------------------------------------------------------------
__global__ __launch_bounds__(256) void wto_kernel(const float* __restrict__ ow,
                                                  unsigned short* __restrict__ wto) {
    int idx = blockIdx.x * 256 + threadIdx.x;      // 0 .. 9215
    int j    = idx & 7;
    int lane = (idx >> 3) & 63;
    int kc   = (idx >> 9) & 1;
    int tap  = idx >> 10;
    int c = kc * 32 + ((lane >> 4) << 3) + j;
    int o = lane & 15;
    wto[idx] = (o < 3) ? f2bf(ow[(tap * 64 + c) * 3 + o]) : (unsigned short)0;
}

// ---------------------------------------------------------------------------
// FULLY FUSED: crop+conv1+relu+conv2+relu+outconv per (10-out-row, box) block.
// LDS = one 16-row x 32 px x 64 ch bf16 slab (65536 B), overwritten in place:
//   P0: bilinear crop rows cb..cb+15 (cb = 10*bx - 2) from features (f32)
//   P1: conv1 SAME on slots 1..14 (acc[7][4]/wave)    P2: writeback (zero OOB)
//   P3: conv2 SAME on slots 2..13 (acc[6][4]/wave)    P4: writeback
//   P5: outconv VALID rows y0..y0+9 (oacc[5]/wave), lanes mcol==cls store f32.
// Intermediates never touch global memory. launch_bounds(256,2): 256-reg cap
// (R5/R6 lesson: tighter caps spill the K-loop to scratch).
// ---------------------------------------------------------------------------
__global__ __launch_bounds__(256, 2) void fused_kernel(const float* __restrict__ feat,
                                                       const float* __restrict__ boxes,
                                                       const int* __restrict__ box_ids,
                                                       const int* __restrict__ cls,
                                                       const unsigned short* __restrict__ wt1,
                                                       const unsigned short* __restrict__ wt2,
                                                       const unsigned short* __restrict__ wto,
                                                       const float* __restrict__ c1b,
                                                       const float* __restrict__ c2b,
                                                       const float* __restrict__ ob,
                                                       float* __restrict__ out) {
    __shared__ unsigned short s_mem[16 * 32 * 64];   // 65536 B

    int gn = blockIdx.y;               // box
    int y0 = blockIdx.x * 10;          // out-row tile base: 0,10,20
    int cb = y0 - 2;                   // crop slab base row (slot 0)
    int t = threadIdx.x;
    int wave = t >> 6, lane = t & 63;
    int quad = lane >> 4, mcol = lane & 15;

    // ---- P0: bilinear crop of 16 rows into LDS (zeros outside [0,32)) ----
    {
        float by1 = boxes[gn * 4 + 0];
        float bx1 = boxes[gn * 4 + 1];
        float by2 = boxes[gn * 4 + 2];
        float bx2 = boxes[gn * 4 + 3];
        const float* fb = feat + (size_t)box_ids[gn] * (HH * WW * CC);

        int px  = t >> 3;              // 0..31
        int cg8 = (t & 7) << 3;        // channel base (8 ch per task)
        float tx  = (float)px / 31.0f;
        float xsf = (bx1 + tx * (bx2 - bx1)) * 191.0f;
        float x0f = fminf(fmaxf(floorf(xsf), 0.0f), 191.0f);
        float wx  = xsf - x0f;
        int x0i = (int)x0f, x1i = min(x0i + 1, 191);
        int ldsbase = px * 64 + SWZ(px, cg8);

#pragma unroll
        for (int s = 0; s < 16; s++) {
            int gr = cb + s;
            unsigned int r4[4] = {0, 0, 0, 0};
            if (gr >= 0 && gr < 32) {
                float tyv = (float)gr / 31.0f;
                float ysf = (by1 + tyv * (by2 - by1)) * 191.0f;
                float y0f = fminf(fmaxf(floorf(ysf), 0.0f), 191.0f);
                float wy  = ysf - y0f;
                int y0i = (int)y0f, y1i = min(y0i + 1, 191);
                const float* p00 = fb + ((size_t)y0i * WW + x0i) * CC + cg8;
                const float* p01 = fb + ((size_t)y0i * WW + x1i) * CC + cg8;
                const float* p10 = fb + ((size_t)y1i * WW + x0i) * CC + cg8;
                const float* p11 = fb + ((size_t)y1i * WW + x1i) * CC + cg8;
#pragma unroll
                for (int h = 0; h < 2; h++) {
                    float4 v00 = *(const float4*)(p00 + 4 * h);
                    float4 v01 = *(const float4*)(p01 + 4 * h);
                    float4 v10 = *(const float4*)(p10 + 4 * h);
                    float4 v11 = *(const float4*)(p11 + 4 * h);
                    const float* a00 = (const float*)&v00;
                    const float* a01 = (const float*)&v01;
                    const float* a10 = (const float*)&v10;
                    const float* a11 = (const float*)&v11;
#pragma unroll
                    for (int i = 0; i < 4; i++) {
                        float top = a00[i] + wx * (a01[i] - a00[i]);
                        float bot = a10[i] + wx * (a11[i] - a10[i]);
                        float v = top + wy * (bot - top);
                        unsigned short b = f2bf(v);
                        int e = 4 * h + i;
                        if (e & 1) r4[e >> 1] |= ((unsigned int)b << 16);
                        else       r4[e >> 1]  = (unsigned int)b;
                    }
                }
            }
            *(uint4*)(s_mem + s * 2048 + ldsbase) = *(uint4*)r4;
        }
    }
    __syncthreads();

    // ---- P1: conv1 SAME on slots 1..14 (28 m-tiles, 7 per wave) ----
    f32x4 acc1[7][4];
#pragma unroll
    for (int nt = 0; nt < 4; nt++) {
        float bv = c1b[(nt << 4) + mcol];
#pragma unroll
        for (int ti = 0; ti < 7; ti++) acc1[ti][nt] = (f32x4){bv, bv, bv, bv};
    }
#pragma unroll
    for (int dy = 0; dy < 3; dy++) {
#pragma unroll
        for (int dx = 0; dx < 3; dx++) {
            int tap = dy * 3 + dx;
#pragma unroll
            for (int kc = 0; kc < 2; kc++) {
                uint4 bfr[4];
#pragma unroll
                for (int nt = 0; nt < 4; nt++)
                    bfr[nt] = *(const uint4*)(wt1 + ((((tap * 2 + kc) * 4 + nt) * 64 + lane) << 3));
#pragma unroll
                for (int ti = 0; ti < 7; ti++) {
                    int mt = wave * 7 + ti;
                    int R  = 1 + (mt >> 1);                 // slot of conv1 row
                    int xs = ((mt & 1) << 4) + mcol + dx - 1;
                    uint4 a = {0, 0, 0, 0};
                    if (xs >= 0 && xs < 32)
                        a = *(const uint4*)(s_mem + ((R - 1 + dy) * 32 + xs) * 64 +
                                            SWZ(xs, (kc << 5) + (quad << 3)));
#pragma unroll
                    for (int nt = 0; nt < 4; nt++)
                        acc1[ti][nt] = __builtin_amdgcn_mfma_f32_16x16x32_bf16(
                            __builtin_bit_cast(bf16x8, a),
                            __builtin_bit_cast(bf16x8, bfr[nt]), acc1[ti][nt], 0, 0, 0);
                }
            }
        }
    }
    __syncthreads();

    // ---- P2: ReLU + bf16 writeback of conv1 rows into slots 1..14 ----
#pragma unroll
    for (int ti = 0; ti < 7; ti++) {
        int mt = wave * 7 + ti;
        int R  = 1 + (mt >> 1);
        int gr = cb + R;                                    // global conv1 row
        bool valid = (gr >= 0 && gr < 32);
        int xb = ((mt & 1) << 4) + (quad << 2);
#pragma unroll
        for (int reg = 0; reg < 4; reg++) {
            int x = xb + reg;
#pragma unroll
            for (int nt = 0; nt < 4; nt++) {
                float v = valid ? fmaxf(acc1[ti][nt][reg], 0.0f) : 0.0f;
                s_mem[(R * 32 + x) * 64 + SWZ(x, (nt << 4) + mcol)] = f2bf(v);
            }
        }
    }
    __syncthreads();

    // ---- P3: conv2 SAME on slots 2..13 (24 m-tiles, 6 per wave) ----
    f32x4 acc2[6][4];
#pragma unroll
    for (int nt = 0; nt < 4; nt++) {
        float bv = c2b[(nt << 4) + mcol];
#pragma unroll
        for (int ti = 0; ti < 6; ti++) acc2[ti][nt] = (f32x4){bv, bv, bv, bv};
    }
#pragma unroll
    for (int dy = 0; dy < 3; dy++) {
#pragma unroll
        for (int dx = 0; dx < 3; dx++) {
            int tap = dy * 3 + dx;
#pragma unroll
            for (int kc = 0; kc < 2; kc++) {
                uint4 bfr[4];
#pragma unroll
                for (int nt = 0; nt < 4; nt++)
                    bfr[nt] = *(const uint4*)(wt2 + ((((tap * 2 + kc) * 4 + nt) * 64 + lane) << 3));
#pragma unroll
                for (int ti = 0; ti < 6; ti++) {
                    int mt = wave * 6 + ti;
                    int R  = 2 + (mt >> 1);                 // slot of conv2 row
                    int xs = ((mt & 1) << 4) + mcol + dx - 1;
                    uint4 a = {0, 0, 0, 0};
                    if (xs >= 0 && xs < 32)
                        a = *(const uint4*)(s_mem + ((R - 1 + dy) * 32 + xs) * 64 +
                                            SWZ(xs, (kc << 5) + (quad << 3)));
#pragma unroll
                    for (int nt = 0; nt < 4; nt++)
                        acc2[ti][nt] = __builtin_amdgcn_mfma_f32_16x16x32_bf16(
                            __builtin_bit_cast(bf16x8, a),
                            __builtin_bit_cast(bf16x8, bfr[nt]), acc2[ti][nt], 0, 0, 0);
                }
            }
        }
    }
    __syncthreads();

    // ---- P4: ReLU + bf16 writeback of conv2 rows into slots 2..13 ----
    // (global rows y0..y0+11 are always inside [0,32) for y0 in {0,10,20})
#pragma unroll
    for (int ti = 0; ti < 6; ti++) {
        int mt = wave * 6 + ti;
        int R  = 2 + (mt >> 1);
        int xb = ((mt & 1) << 4) + (quad << 2);
#pragma unroll
        for (int reg = 0; reg < 4; reg++) {
            int x = xb + reg;
#pragma unroll
            for (int nt = 0; nt < 4; nt++) {
                float v = fmaxf(acc2[ti][nt][reg], 0.0f);
                s_mem[(R * 32 + x) * 64 + SWZ(x, (nt << 4) + mcol)] = f2bf(v);
            }
        }
    }
    __syncthreads();

    // ---- P5: outconv VALID rows y0..y0+9 (20 m-tiles, 5 per wave) ----
    f32x4 oacc[5];
#pragma unroll
    for (int ti = 0; ti < 5; ti++) oacc[ti] = (f32x4){0.f, 0.f, 0.f, 0.f};
#pragma unroll
    for (int dy = 0; dy < 3; dy++) {
#pragma unroll
        for (int dx = 0; dx < 3; dx++) {
            int tap = dy * 3 + dx;
#pragma unroll
            for (int kc = 0; kc < 2; kc++) {
                uint4 bfr = *(const uint4*)(wto + (((tap * 2 + kc) * 64 + lane) << 3));
#pragma unroll
                for (int ti = 0; ti < 5; ti++) {
                    int ot = wave * 5 + ti;
                    int R  = 2 + (ot >> 1) + dy;            // conv2 slot 2..13
                    int xs = ((ot & 1) << 4) + mcol + dx;   // 0..33
                    if (xs > 31) xs = 31;                   // feeds discarded x>=30
                    uint4 a = *(const uint4*)(s_mem + (R * 32 + xs) * 64 +
                                              SWZ(xs, (kc << 5) + (quad << 3)));
                    oacc[ti] = __builtin_amdgcn_mfma_f32_16x16x32_bf16(
                        __builtin_bit_cast(bf16x8, a),
                        __builtin_bit_cast(bf16x8, bfr), oacc[ti], 0, 0, 0);
                }
            }
        }
    }

    int oc = cls[gn];
    if (mcol == oc) {
        float bv = ob[oc];
#pragma unroll
        for (int ti = 0; ti < 5; ti++) {
            int ot = wave * 5 + ti;
            int yo = y0 + (ot >> 1);                        // always < 30
            int xb = ((ot & 1) << 4) + (quad << 2);
#pragma unroll
            for (int reg = 0; reg < 4; reg++) {
                int x = xb + reg;
                if (x < 30)
                    out[(size_t)gn * 900 + yo * 30 + x] = oacc[ti][reg] + bv;
            }
        }
    }
}

// ---------------------------------------------------------------------------
extern "C" void kernel_launch(void* const* d_in, const int* in_sizes, int n_in,
                              void* d_out, int out_size, void* d_ws, size_t ws_size,
                              hipStream_t stream) {
    const float* feat    = (const float*)d_in[0];
    const float* boxes   = (const float*)d_in[1];
    const int*   box_ids = (const int*)d_in[2];
    const int*   cls     = (const int*)d_in[3];
    const float* c1w     = (const float*)d_in[4];
    const float* c1b     = (const float*)d_in[5];
    const float* c2w     = (const float*)d_in[6];
    const float* c2b     = (const float*)d_in[7];
    const float* ow      = (const float*)d_in[8];
    const float* ob      = (const float*)d_in[9];

    unsigned short* wt1 = (unsigned short*)d_ws;
    unsigned short* wt2 = wt1 + 36864;
    unsigned short* wto = wt2 + 36864;

    wt_kernel<<<144, 256, 0, stream>>>(c1w, wt1);
    wt_kernel<<<144, 256, 0, stream>>>(c2w, wt2);
    wto_kernel<<<36, 256, 0, stream>>>(ow, wto);

    fused_kernel<<<dim3(3, NB), 256, 0, stream>>>(feat, boxes, box_ids, cls,
                                                  wt1, wt2, wto, c1b, c2b, ob,
                                                  (float*)d_out);
}

// Round 9
// 440.492 us; speedup vs baseline: 1.2046x; 1.2046x over previous
//
#include <hip/hip_runtime.h>

#define HH 192
#define WW 192
#define CC 64
#define NB 1024

typedef __bf16 bf16x8 __attribute__((ext_vector_type(8)));
typedef float  f32x4  __attribute__((ext_vector_type(4)));

__device__ __forceinline__ unsigned short f2bf(float f) {
    unsigned int u = __builtin_bit_cast(unsigned int, f);
    u += 0x7FFFu + ((u >> 16) & 1u);   // round-to-nearest-even
    return (unsigned short)(u >> 16);
}

// LDS bank swizzle: channel-group XOR by (px & 7). 16B-alignment preserved,
// conflict-free verified R5-R8 (SQ_LDS_BANK_CONFLICT = 0).
#define SWZ(px, c) ((c) ^ (((px) & 7) << 3))

// ---------------------------------------------------------------------------
// Weight pre-transpose: w f32 [tap][c][o] -> bf16 WT[tap][kc][ot][lane][j],
// k = kc*32 + (lane>>4)*8 + j, oc = ot*16 + (lane&15).
// Used as MFMA *A* operand now (A[m=oc][k]) — same register layout.
// ---------------------------------------------------------------------------
__global__ __launch_bounds__(256) void wt_kernel(const float* __restrict__ w,
                                                 unsigned short* __restrict__ wt) {
    int idx = blockIdx.x * 256 + threadIdx.x;      // 0 .. 36863
    int j    = idx & 7;
    int lane = (idx >> 3) & 63;
    int ot   = (idx >> 9) & 3;
    int kc   = (idx >> 11) & 1;
    int tap  = idx >> 12;
    int c = kc * 32 + ((lane >> 4) << 3) + j;
    int o = (ot << 4) + (lane & 15);
    wt[idx] = f2bf(w[(tap * 64 + c) * 64 + o]);
}

// ---------------------------------------------------------------------------
// Out-weight transpose: ow f32 [tap][c][3] -> bf16 A-frag layout, rows (oc)
// padded to 16: WTo[tap][kc][lane][j]
// ---------------------------------------------------------------------------
__global__ __launch_bounds__(256) void wto_kernel(const float* __restrict__ ow,
                                                  unsigned short* __restrict__ wto) {
    int idx = blockIdx.x * 256 + threadIdx.x;      // 0 .. 9215
    int j    = idx & 7;
    int lane = (idx >> 3) & 63;
    int kc   = (idx >> 9) & 1;
    int tap  = idx >> 10;
    int c = kc * 32 + ((lane >> 4) << 3) + j;
    int o = lane & 15;
    wto[idx] = (o < 3) ? f2bf(ow[(tap * 64 + c) * 3 + o]) : (unsigned short)0;
}

// ---------------------------------------------------------------------------
// FULLY FUSED crop+conv1+relu+conv2+relu+outconv. 512 threads (8 waves),
// block = (10-out-row tile, box), 16-slot LDS slab overwritten in place.
// Register discipline (R4-R8 measurements: arch cap=256/w, AGPR cap=256/w):
// every phase holds <= acc[4][4] per wave. MFMA args are (weights=A, act=B)
// so D rows = oc -> lane's 4 acc regs are 4 consecutive channels (cheap
// writebacks). launch_bounds(512,2): caps 128/128, 1 block/CU.
// ---------------------------------------------------------------------------
__global__ __launch_bounds__(512, 2) void fused_kernel(const float* __restrict__ feat,
                                                       const float* __restrict__ boxes,
                                                       const int* __restrict__ box_ids,
                                                       const int* __restrict__ cls,
                                                       const unsigned short* __restrict__ wt1,
                                                       const unsigned short* __restrict__ wt2,
                                                       const unsigned short* __restrict__ wto,
                                                       const float* __restrict__ c1b,
                                                       const float* __restrict__ c2b,
                                                       const float* __restrict__ ob,
                                                       float* __restrict__ out) {
    __shared__ unsigned short s_mem[16 * 32 * 64];   // 65536 B

    int gn = blockIdx.y;               // box
    int y0 = blockIdx.x * 10;          // out-row tile base: 0,10,20
    int cb = y0 - 2;                   // crop slab base row (slot 0)
    int t = threadIdx.x;
    int wave = t >> 6, lane = t & 63;
    int quad = lane >> 4, mcol = lane & 15;

    // ---- P0: bilinear crop of 16 rows into LDS (zeros outside [0,32)) ----
    {
        float by1 = boxes[gn * 4 + 0];
        float bx1 = boxes[gn * 4 + 1];
        float by2 = boxes[gn * 4 + 2];
        float bx2 = boxes[gn * 4 + 3];
        const float* fb = feat + (size_t)box_ids[gn] * (HH * WW * CC);

        int rh  = t >> 8;              // row half: 0 or 1
        int px  = (t >> 3) & 31;
        int cg8 = (t & 7) << 3;
        float tx  = (float)px / 31.0f;
        float xsf = (bx1 + tx * (bx2 - bx1)) * 191.0f;
        float x0f = fminf(fmaxf(floorf(xsf), 0.0f), 191.0f);
        float wx  = xsf - x0f;
        int x0i = (int)x0f, x1i = min(x0i + 1, 191);
        int ldsbase = px * 64 + SWZ(px, cg8);

#pragma unroll 2
        for (int k = 0; k < 8; k++) {
            int s = rh * 8 + k;
            int gr = cb + s;
            unsigned int r4[4] = {0, 0, 0, 0};
            if (gr >= 0 && gr < 32) {
                float tyv = (float)gr / 31.0f;
                float ysf = (by1 + tyv * (by2 - by1)) * 191.0f;
                float y0f = fminf(fmaxf(floorf(ysf), 0.0f), 191.0f);
                float wy  = ysf - y0f;
                int y0i = (int)y0f, y1i = min(y0i + 1, 191);
                const float* p00 = fb + ((size_t)y0i * WW + x0i) * CC + cg8;
                const float* p01 = fb + ((size_t)y0i * WW + x1i) * CC + cg8;
                const float* p10 = fb + ((size_t)y1i * WW + x0i) * CC + cg8;
                const float* p11 = fb + ((size_t)y1i * WW + x1i) * CC + cg8;
#pragma unroll
                for (int h = 0; h < 2; h++) {
                    float4 v00 = *(const float4*)(p00 + 4 * h);
                    float4 v01 = *(const float4*)(p01 + 4 * h);
                    float4 v10 = *(const float4*)(p10 + 4 * h);
                    float4 v11 = *(const float4*)(p11 + 4 * h);
                    const float* a00 = (const float*)&v00;
                    const float* a01 = (const float*)&v01;
                    const float* a10 = (const float*)&v10;
                    const float* a11 = (const float*)&v11;
#pragma unroll
                    for (int i = 0; i < 4; i++) {
                        float top = a00[i] + wx * (a01[i] - a00[i]);
                        float bot = a10[i] + wx * (a11[i] - a10[i]);
                        float v = top + wy * (bot - top);
                        unsigned short b = f2bf(v);
                        int e = 4 * h + i;
                        if (e & 1) r4[e >> 1] |= ((unsigned int)b << 16);
                        else       r4[e >> 1]  = (unsigned int)b;
                    }
                }
            }
            *(uint4*)(s_mem + s * 2048 + ldsbase) = *(uint4*)r4;
        }
    }
    __syncthreads();

    // ---- P1: conv1 SAME on slots 1..14 (28 tiles; mt = wave + 8*ti < 28) ----
    {
        f32x4 acc[4][4];
#pragma unroll
        for (int ot = 0; ot < 4; ot++) {
            float4 bv = *(const float4*)(c1b + (ot << 4) + (quad << 2));
#pragma unroll
            for (int ti = 0; ti < 4; ti++)
                acc[ti][ot] = (f32x4){bv.x, bv.y, bv.z, bv.w};
        }
#pragma unroll
        for (int dy = 0; dy < 3; dy++) {
#pragma unroll
            for (int dx = 0; dx < 3; dx++) {
                int tap = dy * 3 + dx;
#pragma unroll
                for (int kc = 0; kc < 2; kc++) {
                    uint4 wA[4];
#pragma unroll
                    for (int ot = 0; ot < 4; ot++)
                        wA[ot] = *(const uint4*)(wt1 + ((((tap * 2 + kc) * 4 + ot) * 64 + lane) << 3));
#pragma unroll
                    for (int ti = 0; ti < 4; ti++) {
                        int mt = wave + (ti << 3);
                        if (mt < 28) {
                            int R  = 1 + (mt >> 1);
                            int xs = ((mt & 1) << 4) + mcol + dx - 1;
                            uint4 b = {0, 0, 0, 0};
                            if (xs >= 0 && xs < 32)
                                b = *(const uint4*)(s_mem + ((R - 1 + dy) * 32 + xs) * 64 +
                                                    SWZ(xs, (kc << 5) + (quad << 3)));
#pragma unroll
                            for (int ot = 0; ot < 4; ot++)
                                acc[ti][ot] = __builtin_amdgcn_mfma_f32_16x16x32_bf16(
                                    __builtin_bit_cast(bf16x8, wA[ot]),
                                    __builtin_bit_cast(bf16x8, b), acc[ti][ot], 0, 0, 0);
                        }
                    }
                }
            }
        }
        __syncthreads();

        // ---- P2: ReLU + bf16 writeback into slots 1..14 (zero OOB rows) ----
#pragma unroll
        for (int ti = 0; ti < 4; ti++) {
            int mt = wave + (ti << 3);
            if (mt < 28) {
                int R  = 1 + (mt >> 1);
                int gr = cb + R;
                bool valid = (gr >= 0 && gr < 32);
                int px = ((mt & 1) << 4) + mcol;
#pragma unroll
                for (int ot = 0; ot < 4; ot++) {
                    float v0 = valid ? fmaxf(acc[ti][ot][0], 0.0f) : 0.0f;
                    float v1 = valid ? fmaxf(acc[ti][ot][1], 0.0f) : 0.0f;
                    float v2 = valid ? fmaxf(acc[ti][ot][2], 0.0f) : 0.0f;
                    float v3 = valid ? fmaxf(acc[ti][ot][3], 0.0f) : 0.0f;
                    unsigned int lo = (unsigned int)f2bf(v0) | ((unsigned int)f2bf(v1) << 16);
                    unsigned int hi = (unsigned int)f2bf(v2) | ((unsigned int)f2bf(v3) << 16);
                    int ch = (ot << 4) + (quad << 2);
                    *(uint2*)(s_mem + (R * 32 + px) * 64 + SWZ(px, ch)) = (uint2){lo, hi};
                }
            }
        }
    }
    __syncthreads();

    // ---- P3: conv2 SAME on slots 2..13 (24 tiles; mt = wave + 8*ti, ti<3) ----
    {
        f32x4 acc[3][4];
#pragma unroll
        for (int ot = 0; ot < 4; ot++) {
            float4 bv = *(const float4*)(c2b + (ot << 4) + (quad << 2));
#pragma unroll
            for (int ti = 0; ti < 3; ti++)
                acc[ti][ot] = (f32x4){bv.x, bv.y, bv.z, bv.w};
        }
#pragma unroll
        for (int dy = 0; dy < 3; dy++) {
#pragma unroll
            for (int dx = 0; dx < 3; dx++) {
                int tap = dy * 3 + dx;
#pragma unroll
                for (int kc = 0; kc < 2; kc++) {
                    uint4 wA[4];
#pragma unroll
                    for (int ot = 0; ot < 4; ot++)
                        wA[ot] = *(const uint4*)(wt2 + ((((tap * 2 + kc) * 4 + ot) * 64 + lane) << 3));
#pragma unroll
                    for (int ti = 0; ti < 3; ti++) {
                        int mt = wave + (ti << 3);
                        int R  = 2 + (mt >> 1);
                        int xs = ((mt & 1) << 4) + mcol + dx - 1;
                        uint4 b = {0, 0, 0, 0};
                        if (xs >= 0 && xs < 32)
                            b = *(const uint4*)(s_mem + ((R - 1 + dy) * 32 + xs) * 64 +
                                                SWZ(xs, (kc << 5) + (quad << 3)));
#pragma unroll
                        for (int ot = 0; ot < 4; ot++)
                            acc[ti][ot] = __builtin_amdgcn_mfma_f32_16x16x32_bf16(
                                __builtin_bit_cast(bf16x8, wA[ot]),
                                __builtin_bit_cast(bf16x8, b), acc[ti][ot], 0, 0, 0);
                    }
                }
            }
        }
        __syncthreads();

        // ---- P4: ReLU + bf16 writeback into slots 2..13 (always in-image) ----
#pragma unroll
        for (int ti = 0; ti < 3; ti++) {
            int mt = wave + (ti << 3);
            int R  = 2 + (mt >> 1);
            int px = ((mt & 1) << 4) + mcol;
#pragma unroll
            for (int ot = 0; ot < 4; ot++) {
                unsigned int lo = (unsigned int)f2bf(fmaxf(acc[ti][ot][0], 0.0f)) |
                                  ((unsigned int)f2bf(fmaxf(acc[ti][ot][1], 0.0f)) << 16);
                unsigned int hi = (unsigned int)f2bf(fmaxf(acc[ti][ot][2], 0.0f)) |
                                  ((unsigned int)f2bf(fmaxf(acc[ti][ot][3], 0.0f)) << 16);
                int ch = (ot << 4) + (quad << 2);
                *(uint2*)(s_mem + (R * 32 + px) * 64 + SWZ(px, ch)) = (uint2){lo, hi};
            }
        }
    }
    __syncthreads();

    // ---- P5: outconv VALID rows y0..y0+9 (20 tiles; mt = wave + 8*ti < 20) ----
    f32x4 oacc[3];
#pragma unroll
    for (int ti = 0; ti < 3; ti++) oacc[ti] = (f32x4){0.f, 0.f, 0.f, 0.f};
#pragma unroll
    for (int dy = 0; dy < 3; dy++) {
#pragma unroll
        for (int dx = 0; dx < 3; dx++) {
            int tap = dy * 3 + dx;
#pragma unroll
            for (int kc = 0; kc < 2; kc++) {
                uint4 wA = *(const uint4*)(wto + (((tap * 2 + kc) * 64 + lane) << 3));
#pragma unroll
                for (int ti = 0; ti < 3; ti++) {
                    int mt = wave + (ti << 3);
                    if (mt < 20) {
                        int R  = 2 + (mt >> 1) + dy;          // conv2 slot 2..13
                        int xs = ((mt & 1) << 4) + mcol + dx; // 0..33
                        if (xs > 31) xs = 31;                 // feeds discarded x>=30
                        uint4 b = *(const uint4*)(s_mem + (R * 32 + xs) * 64 +
                                                  SWZ(xs, (kc << 5) + (quad << 3)));
                        oacc[ti] = __builtin_amdgcn_mfma_f32_16x16x32_bf16(
                            __builtin_bit_cast(bf16x8, wA),
                            __builtin_bit_cast(bf16x8, b), oacc[ti], 0, 0, 0);
                    }
                }
            }
        }
    }

    // D rows = oc (quad*4+reg), cols = px (mcol). Selected class lives in quad 0.
    int oc = cls[gn];
    if (quad == 0) {
        float bv = ob[oc];
#pragma unroll
        for (int ti = 0; ti < 3; ti++) {
            int mt = wave + (ti << 3);
            if (mt < 20) {
                int r  = mt >> 1;
                int px = ((mt & 1) << 4) + mcol;
                if (px < 30) {
                    float v = (oc == 0) ? oacc[ti][0] : ((oc == 1) ? oacc[ti][1] : oacc[ti][2]);
                    out[(size_t)gn * 900 + (y0 + r) * 30 + px] = v + bv;
                }
            }
        }
    }
}

// ---------------------------------------------------------------------------
extern "C" void kernel_launch(void* const* d_in, const int* in_sizes, int n_in,
                              void* d_out, int out_size, void* d_ws, size_t ws_size,
                              hipStream_t stream) {
    const float* feat    = (const float*)d_in[0];
    const float* boxes   = (const float*)d_in[1];
    const int*   box_ids = (const int*)d_in[2];
    const int*   cls     = (const int*)d_in[3];
    const float* c1w     = (const float*)d_in[4];
    const float* c1b     = (const float*)d_in[5];
    const float* c2w     = (const float*)d_in[6];
    const float* c2b     = (const float*)d_in[7];
    const float* ow      = (const float*)d_in[8];
    const float* ob      = (const float*)d_in[9];

    unsigned short* wt1 = (unsigned short*)d_ws;
    unsigned short* wt2 = wt1 + 36864;
    unsigned short* wto = wt2 + 36864;

    wt_kernel<<<144, 256, 0, stream>>>(c1w, wt1);
    wt_kernel<<<144, 256, 0, stream>>>(c2w, wt2);
    wto_kernel<<<36, 256, 0, stream>>>(ow, wto);

    fused_kernel<<<dim3(3, NB), 512, 0, stream>>>(feat, boxes, box_ids, cls,
                                                  wt1, wt2, wto, c1b, c2b, ob,
                                                  (float*)d_out);
}